// Round 2
// baseline (659.536 us; speedup 1.0000x reference)
//
#include <hip/hip_runtime.h>
#include <stdint.h>

// Problem constants
#define BATCH 512
#define HWIMG 78400      // 280*280
#define WROW  280
#define PNUM  100        // 10x10 patches
#define FNUM  16
#define ONUM  10

__global__ __launch_bounds__(256) void init_out(const float* __restrict__ dec_b,
                                                float* __restrict__ out) {
    int i = blockIdx.x * 256 + threadIdx.x;
    if (i < BATCH * ONUM) out[i] = dec_b[i % ONUM];
}

// One wave per block: (patch p, 16 batches, all 16 filters). No LDS, no barriers.
// EXPLICIT software pipeline: register double-buffer (av[2][8], wv[2][4]) with a
// guaranteed prefetch distance of one full row across the whole 28-row stream.
// Every m-step: issue next row's 12 float4 loads FIRST, then run the current row's
// 128 FMAs. Buffer parity is compile-time (m-loop unrolled), so no scratch (rule #20).
// Pointer advance happens inside the m==3 slot so all load offsets are small
// compile-time immediates (max 3360 B < 4095 B signed-13-bit range).
//   Lane map: kg = t&7 (float4 column, kg==7 duplicates kg==0 and is masked),
//   fg = (t>>3)&3 (filter quad), bg = t>>5 (batch oct).
__global__ __launch_bounds__(64, 3) void lcn_pipe(
    const float* __restrict__ x,      // (512,1,280,280)
    const float* __restrict__ weight, // (1600,1,28,28)  index (f*100+p)*784
    const float* __restrict__ bias,   // (1600,1)        index  f*100+p
    const float* __restrict__ dec_w,  // (10,1600)       index  o*1600+f*100+p
    float* __restrict__ out)          // (512,10) pre-initialized with dec_b
{
    const int t  = threadIdx.x;       // 0..63
    const int kg = t & 7;
    const int fg = (t >> 3) & 3;
    const int bg = t >> 5;
    const int bx = blockIdx.x;        // 0..3199
    const int p    = bx >> 5;         // 32 consecutive blocks share p -> warm w in L2
    const int bgrp = bx & 31;
    const int b0   = bgrp * 16;
    const int pr = p / 10, pc = p % 10;
    const int kge = (kg < 7) ? kg : 0;

    // 32-bit ELEMENT offsets -> SGPR-base + 32-bit VGPR-offset addressing.
    uint32_t xoff[8];
#pragma unroll
    for (int i = 0; i < 8; ++i)
        xoff[i] = (uint32_t)(b0 + bg * 8 + i) * HWIMG
                + (uint32_t)(pr * 28) * WROW + pc * 28 + kge * 4;
    uint32_t woff[4];
#pragma unroll
    for (int j = 0; j < 4; ++j)
        woff[j] = (uint32_t)((fg * 4 + j) * PNUM + p) * 784 + kge * 4;

    float acc[8][4];
#pragma unroll
    for (int i = 0; i < 8; ++i)
#pragma unroll
        for (int j = 0; j < 4; ++j) acc[i][j] = 0.f;

    float4 av[2][8];
    float4 wv[2][4];

    // Prologue: row 0 -> buffer 0.
#pragma unroll
    for (int i = 0; i < 8; ++i)
        av[0][i] = *reinterpret_cast<const float4*>(x + xoff[i]);
#pragma unroll
    for (int j = 0; j < 4; ++j)
        wv[0][j] = *reinterpret_cast<const float4*>(weight + woff[j]);

    // 28 rows = 7 chunks x 4. Row r=c*4+m computes from buf[m&1], prefetches
    // row r+1 into buf[(m+1)&1].
#pragma unroll 1
    for (int c = 0; c < 7; ++c) {
#pragma unroll
        for (int m = 0; m < 4; ++m) {
            const int cur = m & 1;
            const int nxt = cur ^ 1;

            // ---- prefetch row r+1 (issued before the FMAs that hide it)
            if (m < 3) {
#pragma unroll
                for (int i = 0; i < 8; ++i)
                    av[nxt][i] = *reinterpret_cast<const float4*>(
                        x + xoff[i] + (m + 1) * WROW);
#pragma unroll
                for (int j = 0; j < 4; ++j)
                    wv[nxt][j] = *reinterpret_cast<const float4*>(
                        weight + woff[j] + (m + 1) * 28);
            } else {
#pragma unroll
                for (int i = 0; i < 8; ++i) xoff[i] += 4 * WROW;
#pragma unroll
                for (int j = 0; j < 4; ++j) woff[j] += 4 * 28;
                if (c < 6) {
#pragma unroll
                    for (int i = 0; i < 8; ++i)
                        av[nxt][i] = *reinterpret_cast<const float4*>(x + xoff[i]);
#pragma unroll
                    for (int j = 0; j < 4; ++j)
                        wv[nxt][j] = *reinterpret_cast<const float4*>(weight + woff[j]);
                }
            }

            // ---- compute current row from buf[cur]
#pragma unroll
            for (int i = 0; i < 8; ++i) {
                const float4 a = av[cur][i];
#pragma unroll
                for (int j = 0; j < 4; ++j) {
                    acc[i][j] = fmaf(a.x, wv[cur][j].x, acc[i][j]);
                    acc[i][j] = fmaf(a.y, wv[cur][j].y, acc[i][j]);
                    acc[i][j] = fmaf(a.z, wv[cur][j].z, acc[i][j]);
                    acc[i][j] = fmaf(a.w, wv[cur][j].w, acc[i][j]);
                }
            }
        }
    }

    // kg==7 computed duplicated data: zero it.
    const float km = (kg < 7) ? 1.f : 0.f;
#pragma unroll
    for (int i = 0; i < 8; ++i)
#pragma unroll
        for (int j = 0; j < 4; ++j) acc[i][j] *= km;

    // Reduce over kg (lane bits 0..2) — butterfly; all lanes end with the sum.
#pragma unroll
    for (int d = 1; d < 8; d <<= 1)
#pragma unroll
        for (int i = 0; i < 8; ++i)
#pragma unroll
            for (int j = 0; j < 4; ++j)
                acc[i][j] += __shfl_xor(acc[i][j], d, 64);

    // bias + relu
    float y[8][4];
#pragma unroll
    for (int j = 0; j < 4; ++j) {
        const float bs = bias[(fg * 4 + j) * PNUM + p];
#pragma unroll
        for (int i = 0; i < 8; ++i) {
            float v = acc[i][j] + bs;
            y[i][j] = v > 0.f ? v : 0.f;
        }
    }

    // Decoder: split the 10 outputs across kg lanes 0..4 (2 outputs each).
    float po[8][2];
    const int  o0  = kg * 2;
    const bool act = (kg < 5);
    if (act) {
        float dwv[4][2];
#pragma unroll
        for (int j = 0; j < 4; ++j)
#pragma unroll
            for (int oo = 0; oo < 2; ++oo)
                dwv[j][oo] = dec_w[(size_t)(o0 + oo) * (PNUM * FNUM) + (fg * 4 + j) * PNUM + p];
#pragma unroll
        for (int i = 0; i < 8; ++i)
#pragma unroll
            for (int oo = 0; oo < 2; ++oo) {
                float s = 0.f;
#pragma unroll
                for (int j = 0; j < 4; ++j) s = fmaf(y[i][j], dwv[j][oo], s);
                po[i][oo] = s;
            }
    } else {
#pragma unroll
        for (int i = 0; i < 8; ++i) { po[i][0] = 0.f; po[i][1] = 0.f; }
    }

    // Reduce over fg (lane bits 3..4); kg/bg bits preserved so zero lanes stay isolated.
#pragma unroll
    for (int d = 8; d < 32; d <<= 1)
#pragma unroll
        for (int i = 0; i < 8; ++i)
#pragma unroll
            for (int oo = 0; oo < 2; ++oo)
                po[i][oo] += __shfl_xor(po[i][oo], d, 64);

    if (act && fg == 0) {
#pragma unroll
        for (int i = 0; i < 8; ++i)
#pragma unroll
            for (int oo = 0; oo < 2; ++oo)
                atomicAdd(&out[(size_t)(b0 + bg * 8 + i) * ONUM + o0 + oo], po[i][oo]);
    }
}

extern "C" void kernel_launch(void* const* d_in, const int* in_sizes, int n_in,
                              void* d_out, int out_size, void* d_ws, size_t ws_size,
                              hipStream_t stream) {
    const float* x     = (const float*)d_in[0];
    const float* w     = (const float*)d_in[1];
    const float* bias  = (const float*)d_in[2];
    const float* dec_w = (const float*)d_in[3];
    const float* dec_b = (const float*)d_in[4];
    float* out = (float*)d_out;

    init_out<<<(BATCH * ONUM + 255) / 256, 256, 0, stream>>>(dec_b, out);
    lcn_pipe<<<(BATCH / 16) * PNUM, 64, 0, stream>>>(x, w, bias, dec_w, out);
}